// Round 1
// baseline (1122.373 us; speedup 1.0000x reference)
//
#include <hip/hip_runtime.h>
#include <stdint.h>

// 2-layer BiLSTM, T=512, B=256, H=128 (gates 4H=512), then FC [2H]->6 on last step.
// Strategy: batch-parallel persistent recurrence. One block per (batch, direction).
// Weights resident in VGPRs as packed f16 pairs, v_dot2_f32_f16 (fp32 accum).
// Layer-1 backward needs only ONE step (reverse-scan output at t=T-1 uses zero carry).

#define TT 512
#define BATCH 256
#define HH 128
#define GG 512  // 4H

typedef _Float16 f16;
typedef _Float16 f16x2 __attribute__((ext_vector_type(2)));

__device__ __forceinline__ float sigf(float x) {
    return __builtin_amdgcn_rcpf(1.0f + __expf(-x));
}
__device__ __forceinline__ float tanh_fast(float x) {
    // tanh(x) = 1 - 2/(exp(2x)+1); inf-safe at both ends
    return 1.0f - 2.0f * __builtin_amdgcn_rcpf(1.0f + __expf(2.0f * x));
}
__device__ __forceinline__ f16x2 pack2(float a, float b) {
    f16x2 r; r.x = (f16)a; r.y = (f16)b; return r;
}
__device__ __forceinline__ float fdot2(f16x2 a, uint32_t braw, float c) {
    return __builtin_amdgcn_fdot2(a, __builtin_bit_cast(f16x2, braw), c, false);
}

// ---------------- Layer 0, both directions ----------------
// grid: 512 blocks (b = bid&255, dir = bid>>8), 512 threads (thread = gate row j)
__global__ __launch_bounds__(512, 4) void lstm_l0(
    const float* __restrict__ x,      // [B][T][3]
    const float* __restrict__ Wih_f,  // [512][3]
    const float* __restrict__ Whh_f,  // [512][128]
    const float* __restrict__ b_f,    // [512]
    const float* __restrict__ Wih_b,
    const float* __restrict__ Whh_b,
    const float* __restrict__ b_b,
    f16* __restrict__ h1)             // [T][B][256]  (fwd half 0:128, bwd 128:256)
{
    const int tid = threadIdx.x;
    const int b   = blockIdx.x & 255;
    const int dir = blockIdx.x >> 8;

    const float* Wih = dir ? Wih_b : Wih_f;
    const float* Whh = dir ? Whh_b : Whh_f;
    const float* bia = dir ? b_b   : b_f;

    __shared__ float x_lds[TT * 3];
    __shared__ uint4 hpair4[16];      // 64 u32 = 128 f16 (recurrent h)
    __shared__ float gates[GG];

    // stage this batch row's x (6 KB)
    for (int i = tid; i < TT * 3; i += 512) x_lds[i] = x[b * (TT * 3) + i];

    // per-thread weights
    const float wx0 = Wih[tid * 3 + 0];
    const float wx1 = Wih[tid * 3 + 1];
    const float wx2 = Wih[tid * 3 + 2];
    const float bias = bia[tid];
    f16x2 wh[64];
    const float4* Whh4 = (const float4*)(Whh + tid * 128);
#pragma unroll
    for (int q = 0; q < 32; ++q) {
        float4 w4 = Whh4[q];
        wh[2 * q + 0] = pack2(w4.x, w4.y);
        wh[2 * q + 1] = pack2(w4.z, w4.w);
    }

    if (tid < 16) hpair4[tid] = make_uint4(0, 0, 0, 0);
    float c_reg = 0.0f;
    __syncthreads();

    for (int s = 0; s < TT; ++s) {
        const int time = dir ? (TT - 1 - s) : s;
        float acc = bias + wx0 * x_lds[time * 3 + 0]
                         + wx1 * x_lds[time * 3 + 1]
                         + wx2 * x_lds[time * 3 + 2];
#pragma unroll
        for (int q = 0; q < 16; ++q) {
            uint4 hv = hpair4[q];  // LDS broadcast read (uniform addr)
            acc = fdot2(wh[4 * q + 0], hv.x, acc);
            acc = fdot2(wh[4 * q + 1], hv.y, acc);
            acc = fdot2(wh[4 * q + 2], hv.z, acc);
            acc = fdot2(wh[4 * q + 3], hv.w, acc);
        }
        gates[tid] = acc;
        __syncthreads();
        if (tid < HH) {
            const float gi = gates[tid];
            const float gf = gates[tid + 128];
            const float gg = gates[tid + 256];
            const float go = gates[tid + 384];
            c_reg = sigf(gf) * c_reg + sigf(gi) * tanh_fast(gg);
            const float h = sigf(go) * tanh_fast(c_reg);
            const f16 hf = (f16)h;
            ((f16*)hpair4)[tid] = hf;
            h1[(size_t)(time * BATCH + b) * 256 + dir * 128 + tid] = hf;
        }
        __syncthreads();
    }
}

// ---------------- Layer 1 forward + 1-step backward + FC ----------------
// grid: 256 blocks (batch), 512 threads (gate row j)
__global__ __launch_bounds__(512, 2) void lstm_l1(
    const f16* __restrict__ h1,       // [T][B][256]
    const float* __restrict__ Wih_f,  // [512][256]
    const float* __restrict__ Whh_f,  // [512][128]
    const float* __restrict__ b_f,
    const float* __restrict__ Wih_b,  // [512][256] (backward, single step)
    const float* __restrict__ b_b,
    const float* __restrict__ Wfc,    // [6][256]
    const float* __restrict__ bfc,    // [6]
    float* __restrict__ out)          // [B][6]
{
    const int tid = threadIdx.x;
    const int b   = blockIdx.x;

    __shared__ uint4 hin4[32];        // 128 u32 = 256 f16 : h1[t][b][:]
    __shared__ uint4 hpair4[16];      // recurrent h (128 f16)
    __shared__ float gates[GG];
    __shared__ float h2[256];         // concat(h2f, h2b) f32

    const uint32_t* h1u = (const uint32_t*)h1;  // pair view

    const float bias = b_f[tid];
    f16x2 wi[128];
    const float4* Wih4 = (const float4*)(Wih_f + tid * 256);
#pragma unroll
    for (int q = 0; q < 64; ++q) {
        float4 w4 = Wih4[q];
        wi[2 * q + 0] = pack2(w4.x, w4.y);
        wi[2 * q + 1] = pack2(w4.z, w4.w);
    }
    f16x2 wh[64];
    const float4* Whh4 = (const float4*)(Whh_f + tid * 128);
#pragma unroll
    for (int q = 0; q < 32; ++q) {
        float4 w4 = Whh4[q];
        wh[2 * q + 0] = pack2(w4.x, w4.y);
        wh[2 * q + 1] = pack2(w4.z, w4.w);
    }

    if (tid < 16) hpair4[tid] = make_uint4(0, 0, 0, 0);
    if (tid < 128) ((uint32_t*)hin4)[tid] = h1u[(size_t)(0 * BATCH + b) * 128 + tid];
    float c_reg = 0.0f, h_reg = 0.0f;
    __syncthreads();

    for (int t = 0; t < TT; ++t) {
        uint32_t nextv = 0;
        if (tid < 128 && t + 1 < TT)
            nextv = h1u[(size_t)((t + 1) * BATCH + b) * 128 + tid];  // prefetch
        float acc = bias;
#pragma unroll
        for (int q = 0; q < 32; ++q) {
            uint4 hv = hin4[q];
            acc = fdot2(wi[4 * q + 0], hv.x, acc);
            acc = fdot2(wi[4 * q + 1], hv.y, acc);
            acc = fdot2(wi[4 * q + 2], hv.z, acc);
            acc = fdot2(wi[4 * q + 3], hv.w, acc);
        }
#pragma unroll
        for (int q = 0; q < 16; ++q) {
            uint4 hv = hpair4[q];
            acc = fdot2(wh[4 * q + 0], hv.x, acc);
            acc = fdot2(wh[4 * q + 1], hv.y, acc);
            acc = fdot2(wh[4 * q + 2], hv.z, acc);
            acc = fdot2(wh[4 * q + 3], hv.w, acc);
        }
        gates[tid] = acc;
        __syncthreads();
        if (tid < HH) {
            const float gi = gates[tid];
            const float gf = gates[tid + 128];
            const float gg = gates[tid + 256];
            const float go = gates[tid + 384];
            c_reg = sigf(gf) * c_reg + sigf(gi) * tanh_fast(gg);
            h_reg = sigf(go) * tanh_fast(c_reg);
            ((f16*)hpair4)[tid] = (f16)h_reg;
            if (t + 1 < TT) ((uint32_t*)hin4)[tid] = nextv;  // stage next input
        }
        __syncthreads();
    }

    // h2 forward half (f32 registers, no f16 rounding here)
    if (tid < HH) h2[tid] = h_reg;

    // layer-1 backward: exactly one step on h1[T-1] (still in hin4), zero carry
    {
        float acc = b_b[tid];
        const float4* Wb4 = (const float4*)(Wih_b + tid * 256);
#pragma unroll 8
        for (int q = 0; q < 32; ++q) {
            uint4 hv = hin4[q];
            float4 w0 = Wb4[2 * q + 0];
            float4 w1 = Wb4[2 * q + 1];
            f16x2 p0 = __builtin_bit_cast(f16x2, hv.x);
            f16x2 p1 = __builtin_bit_cast(f16x2, hv.y);
            f16x2 p2 = __builtin_bit_cast(f16x2, hv.z);
            f16x2 p3 = __builtin_bit_cast(f16x2, hv.w);
            acc += w0.x * (float)p0.x + w0.y * (float)p0.y
                 + w0.z * (float)p1.x + w0.w * (float)p1.y;
            acc += w1.x * (float)p2.x + w1.y * (float)p2.y
                 + w1.z * (float)p3.x + w1.w * (float)p3.y;
        }
        gates[tid] = acc;
    }
    __syncthreads();
    if (tid < HH) {
        const float gi = gates[tid];
        const float gg = gates[tid + 256];
        const float go = gates[tid + 384];
        const float c0 = sigf(gi) * tanh_fast(gg);   // f-gate * 0 drops out
        h2[128 + tid] = sigf(go) * tanh_fast(c0);
    }
    __syncthreads();

    // FC: [6][256] @ h2 — tiny, once per block
    if (tid < 6) {
        float acc = bfc[tid];
        for (int k = 0; k < 256; ++k) acc += Wfc[tid * 256 + k] * h2[k];
        out[b * 6 + tid] = acc;
    }
}

extern "C" void kernel_launch(void* const* d_in, const int* in_sizes, int n_in,
                              void* d_out, int out_size, void* d_ws, size_t ws_size,
                              hipStream_t stream) {
    const float* x     = (const float*)d_in[0];
    const float* Wih0f = (const float*)d_in[1];
    const float* Whh0f = (const float*)d_in[2];
    const float* b0f   = (const float*)d_in[3];
    const float* Wih0b = (const float*)d_in[4];
    const float* Whh0b = (const float*)d_in[5];
    const float* b0b   = (const float*)d_in[6];
    const float* Wih1f = (const float*)d_in[7];
    const float* Whh1f = (const float*)d_in[8];
    const float* b1f   = (const float*)d_in[9];
    const float* Wih1b = (const float*)d_in[10];
    // d_in[11] = W_hh_l1b: unused (backward layer-1 carry is zero at t=T-1)
    const float* b1b   = (const float*)d_in[12];
    const float* Wfc   = (const float*)d_in[13];
    const float* bfc   = (const float*)d_in[14];
    float* out = (float*)d_out;
    f16* h1 = (f16*)d_ws;  // 512*256*256 f16 = 64 MiB

    hipLaunchKernelGGL(lstm_l0, dim3(512), dim3(512), 0, stream,
                       x, Wih0f, Whh0f, b0f, Wih0b, Whh0b, b0b, h1);
    hipLaunchKernelGGL(lstm_l1, dim3(256), dim3(512), 0, stream,
                       h1, Wih1f, Whh1f, b1f, Wih1b, b1b, Wfc, bfc, out);
}